// Round 6
// baseline (296.874 us; speedup 1.0000x reference)
//
#include <hip/hip_runtime.h>

// Problem constants (from reference): nq=nm=128, nkappa=16, d=48, ng=64
#define NQ   128
#define NM   128
#define ND   48
#define NGV  64
#define NAK  48              // 3 * nkappa = flattened (alpha, kappa)
#define RTOL_C 1e-5f
#define ATOL_C 1e-8f
#define SCALE_C (1.0f / 128.0f)   // Omega / tilde_Omega / ng = 1/2/64

// clang-native vector type: __builtin_nontemporal_load requires a native
// vector (HIP's float4 is a class and is rejected).
typedef float f32x4 __attribute__((ext_vector_type(4)));

// ---------------------------------------------------------------------------
// Kernel 1: zero P accumulator + compute per-q-point active-g bitmask.
// grid = 64 x 256  (covers the 16384-element P zeroing; first 128 threads
// also compute the mask bits)
// ---------------------------------------------------------------------------
__global__ __launch_bounds__(256) void k_prep(
    const float* __restrict__ q, const float* __restrict__ gv,
    const float* __restrict__ G, const float* __restrict__ Q,
    unsigned long long* __restrict__ mbits, float* __restrict__ P)
{
    int gid = blockIdx.x * 256 + threadIdx.x;
    if (gid < NQ * NM) P[gid] = 0.0f;
    if (gid < NQ) {
        int i = gid;
        float qx = q[i*3+0], qy = q[i*3+1], qz = q[i*3+2];
        float Qx = Q[i*3+0], Qy = Q[i*3+1], Qz = Q[i*3+2];
        float Gx = G[0], Gy = G[1], Gz = G[2];
        unsigned long long bits = 0ull;
        for (int g = 0; g < NGV; ++g) {
            float ux = qx + gv[g*3+0] - Gx;
            float uy = qy + gv[g*3+1] - Gy;
            float uz = qz + gv[g*3+2] - Gz;
            bool ok = (fabsf(Qx - ux) <= ATOL_C + RTOL_C * fabsf(ux)) &&
                      (fabsf(Qy - uy) <= ATOL_C + RTOL_C * fabsf(uy)) &&
                      (fabsf(Qz - uz) <= ATOL_C + RTOL_C * fabsf(uz));
            if (ok) bits |= (1ull << g);
        }
        mbits[i] = bits;
    }
}

// ---------------------------------------------------------------------------
// Kernel 2 (the heavy one): stream e_tilde once, compute masked |dot|^2 sums.
//   P[i,m] += scale * sum_{g active(i)} sum_{ak in chunk} |dot_d|^2
// grid = 1024 blocks: bid = m*8 + itile*4 + chunk ; block = 256 threads.
// 4-lane group per q-point i; lane sub owns d in [sub*12, sub*12+12).
// e_tilde rows: 3x nontemporal f32x4 (streamed once — keep out of L2 so the
// hot e[:, :, g_active, :] slice (~1.2 MB, re-read once per mode m) stays
// L2-resident). e gathers: 4B/lane but 16 consecutive-i lanes share cache
// lines, and the slice is cache-hot after first touch.
// ---------------------------------------------------------------------------
__global__ __launch_bounds__(256) void k_main(
    const float* __restrict__ et,   // [3,16,128,128,48] -> [ak][m][i][d]
    const float* __restrict__ e,    // [3,16,48,64,128]  -> [ak][d][g][i]
    const unsigned long long* __restrict__ mbits,
    float* __restrict__ P)          // [i][m]
{
    int bid   = blockIdx.x;
    int m     = bid >> 3;
    int itile = (bid >> 2) & 1;
    int chunk = bid & 3;            // ak range [chunk*12, chunk*12+12)

    int tid = threadIdx.x;
    int grp = tid >> 2;             // 0..63 -> i within tile
    int sub = tid & 3;              // 0..3  -> d quarter
    int i   = itile * 64 + grp;
    int d0  = sub * 12;

    unsigned long long mb = mbits[i];
    float acc = 0.0f;

#pragma unroll 2
    for (int akx = 0; akx < 12; ++akx) {
        int ak = chunk * 12 + akx;
        // e_tilde row for (ak, m, i), this lane's 12 d's — nontemporal stream
        const float* rowt = et + ((((size_t)ak * NM + m) * NQ + i) * ND + d0);
        f32x4 t0 = __builtin_nontemporal_load(reinterpret_cast<const f32x4*>(rowt + 0));
        f32x4 t1 = __builtin_nontemporal_load(reinterpret_cast<const f32x4*>(rowt + 4));
        f32x4 t2 = __builtin_nontemporal_load(reinterpret_cast<const f32x4*>(rowt + 8));

        // base pointer into e for (ak, d0, *, i); d stride = 64*128 = 8192
        const float* ep = e + (((size_t)ak * ND + d0) * NGV * NQ + i);

        unsigned long long mm = mb;
        while (mm) {
            int g = __ffsll(mm) - 1;
            mm &= (mm - 1);
            const float* eg = ep + (size_t)g * NQ;
            float dot;
            dot  = t0.x * eg[0*8192] + t0.y * eg[1*8192];
            dot += t0.z * eg[2*8192] + t0.w * eg[3*8192];
            dot += t1.x * eg[4*8192] + t1.y * eg[5*8192];
            dot += t1.z * eg[6*8192] + t1.w * eg[7*8192];
            dot += t2.x * eg[8*8192] + t2.y * eg[9*8192];
            dot += t2.z * eg[10*8192] + t2.w * eg[11*8192];
            // complete the 48-length dot across the 4-lane group
            dot += __shfl_xor(dot, 1, 4);
            dot += __shfl_xor(dot, 2, 4);
            acc += dot * dot;       // all 4 lanes redundantly (uniform)
        }
    }

    if (sub == 0) {
        atomicAdd(&P[(size_t)i * NM + m], acc * SCALE_C);
    }
}

// ---------------------------------------------------------------------------
// Kernel 3: A[m] = sum_k (omega[k]==omega[m]) * P[k,m]; out[i,m] = A[m].
// grid = 32 blocks x 256 threads; A recomputed per block (cheap, L2-resident).
// ---------------------------------------------------------------------------
__global__ __launch_bounds__(256) void k_final(
    const float* __restrict__ omega, const float* __restrict__ P,
    float* __restrict__ out)
{
    __shared__ float A[NM];
    int tid = threadIdx.x;
    if (tid < NM) {
        float om  = omega[tid];
        float acc = 0.0f;
        for (int k = 0; k < NM; ++k) {
            if (omega[k] == om) acc += P[(size_t)k * NM + tid];
        }
        A[tid] = acc;
    }
    __syncthreads();
    int base = blockIdx.x * 512;
    for (int idx = tid; idx < 512; idx += 256) {
        int o = base + idx;
        out[o] = A[o & (NM - 1)];
    }
}

// ---------------------------------------------------------------------------
extern "C" void kernel_launch(void* const* d_in, const int* in_sizes, int n_in,
                              void* d_out, int out_size, void* d_ws, size_t ws_size,
                              hipStream_t stream)
{
    const float* q     = (const float*)d_in[0];   // [128,3]
    const float* omega = (const float*)d_in[1];   // [128]
    const float* et    = (const float*)d_in[2];   // [3,16,128,128,48]
    const float* e     = (const float*)d_in[3];   // [3,16,48,64,128]
    const float* gv    = (const float*)d_in[4];   // [64,3]
    const float* G     = (const float*)d_in[5];   // [3]
    const float* Q     = (const float*)d_in[6];   // [128,3]
    float* out = (float*)d_out;                   // [128,128]

    // workspace layout: mbits (128 x u64) at 0, P (16384 f32) at +4096
    unsigned long long* mbits = (unsigned long long*)d_ws;
    float* P = (float*)((char*)d_ws + 4096);

    k_prep<<<64, 256, 0, stream>>>(q, gv, G, Q, mbits, P);
    k_main<<<1024, 256, 0, stream>>>(et, e, mbits, P);
    k_final<<<32, 256, 0, stream>>>(omega, P, out);
}

// Round 8
// 286.155 us; speedup vs baseline: 1.0375x; 1.0375x over previous
//
#include <hip/hip_runtime.h>

// Problem constants: nq=nm=128, nkappa=16, d=48, ng=64
#define NQ   128
#define NM   128
#define ND   48
#define NGV  64
#define NAK  48              // 3 * nkappa flattened (alpha, kappa)
#define RTOL_C 1e-5f
#define ATOL_C 1e-8f
#define SCALE_C (1.0f / 128.0f)   // Omega / tilde_Omega / ng = 1/2/64

typedef float f32x4 __attribute__((ext_vector_type(4)));

// d_ws layout (ws ~576 MiB, poisoned 0xAA every iteration — everything
// rewritten each call):
//   glist  u8 [128][64]   at byte 0        (8 KB)   active-g list per i
//   gcount int[128]       at 8192          (512 B)
//   P      f32[128*128]   at 16384         (64 KB)
//   ec     f32[64][48][128][48] at 1 MB    (<=75.5 MB, slot-major compacted e)
#define WS_GLIST   0
#define WS_GCOUNT  8192
#define WS_P       16384
#define WS_EC      (1u << 20)

// ---------------------------------------------------------------------------
// Kernel 1: zero P; compute per-i active-g list (mask-first: kills the 64x
// wasted einsum work in the reference).
// ---------------------------------------------------------------------------
__global__ __launch_bounds__(256) void k_prep(
    const float* __restrict__ q, const float* __restrict__ gv,
    const float* __restrict__ G, const float* __restrict__ Q,
    unsigned char* __restrict__ glist, int* __restrict__ gcount,
    float* __restrict__ P)
{
    int gid = blockIdx.x * 256 + threadIdx.x;
    if (gid < NQ * NM) P[gid] = 0.0f;
    if (gid < NQ) {
        int i = gid;
        float qx = q[i*3+0], qy = q[i*3+1], qz = q[i*3+2];
        float Qx = Q[i*3+0], Qy = Q[i*3+1], Qz = Q[i*3+2];
        float Gx = G[0], Gy = G[1], Gz = G[2];
        int cnt = 0;
        for (int g = 0; g < NGV; ++g) {
            float ux = qx + gv[g*3+0] - Gx;
            float uy = qy + gv[g*3+1] - Gy;
            float uz = qz + gv[g*3+2] - Gz;
            bool ok = (fabsf(Qx - ux) <= ATOL_C + RTOL_C * fabsf(ux)) &&
                      (fabsf(Qy - uy) <= ATOL_C + RTOL_C * fabsf(uy)) &&
                      (fabsf(Qz - uz) <= ATOL_C + RTOL_C * fabsf(uz));
            if (ok) { glist[i*NGV + cnt] = (unsigned char)g; ++cnt; }
        }
        gcount[i] = cnt;
    }
}

// ---------------------------------------------------------------------------
// Kernel 2: compact e's active columns into ec[slot][ak][i][d] so k_main reads
// both operands with identical, coalesced 16B layouts. Volume ~1.2 MB/slot.
// One thread per (ak, d, i); reads coalesced along i, scattered 4B writes
// (volume tiny, L2 absorbs).
// ---------------------------------------------------------------------------
__global__ __launch_bounds__(256) void k_gather(
    const float* __restrict__ e,            // [ak][d][g][i]
    const unsigned char* __restrict__ glist,
    const int* __restrict__ gcount,
    float* __restrict__ ec)                 // [slot][ak][i][d]
{
    int t = blockIdx.x * 256 + threadIdx.x;   // 48*48*128 = 294912 threads
    int i  = t & (NQ - 1);
    int d  = (t >> 7) % ND;
    int ak = t / (NQ * ND);
    int gc = gcount[i];
    for (int s = 0; s < gc; ++s) {
        int g = glist[i*NGV + s];
        float v = e[(((size_t)ak * ND + d) * NGV + g) * NQ + i];
        ec[(((size_t)s * NAK + ak) * NQ + i) * ND + d] = v;
    }
}

// ---------------------------------------------------------------------------
// Kernel 3 (heavy): stream e_tilde (151 MB) exactly once; ec is L2-resident.
// grid = 1024: bid = m*8 + itile*4 + chunk. 4-lane group per i; lane sub owns
// d in [sub*12, sub*12+12). Per (akx, slot): 3+3 coalesced f32x4 loads,
// 12 FMA, 2 shfl, 1 square-acc.
// ---------------------------------------------------------------------------
__global__ __launch_bounds__(256) void k_main(
    const float* __restrict__ et,   // [ak][m][i][d]
    const float* __restrict__ ec,   // [slot][ak][i][d]
    const int* __restrict__ gcount,
    float* __restrict__ P)          // [i][m]
{
    int bid   = blockIdx.x;
    int m     = bid >> 3;
    int itile = (bid >> 2) & 1;
    int chunk = bid & 3;            // ak in [chunk*12, chunk*12+12)

    int tid = threadIdx.x;
    int i   = itile * 64 + (tid >> 2);
    int sub = tid & 3;
    int d0  = sub * 12;

    int gc = gcount[i];
    float acc = 0.0f;

    for (int akx = 0; akx < 12; ++akx) {
        int ak = chunk * 12 + akx;
        const float* rowt = et + ((((size_t)ak * NM + m) * NQ + i) * ND + d0);
        f32x4 t0 = *reinterpret_cast<const f32x4*>(rowt + 0);
        f32x4 t1 = *reinterpret_cast<const f32x4*>(rowt + 4);
        f32x4 t2 = *reinterpret_cast<const f32x4*>(rowt + 8);

        for (int s = 0; s < gc; ++s) {
            const float* rowc = ec + ((((size_t)s * NAK + ak) * NQ + i) * ND + d0);
            f32x4 c0 = *reinterpret_cast<const f32x4*>(rowc + 0);
            f32x4 c1 = *reinterpret_cast<const f32x4*>(rowc + 4);
            f32x4 c2 = *reinterpret_cast<const f32x4*>(rowc + 8);
            float dot;
            dot  = t0.x*c0.x + t0.y*c0.y + t0.z*c0.z + t0.w*c0.w;
            dot += t1.x*c1.x + t1.y*c1.y + t1.z*c1.z + t1.w*c1.w;
            dot += t2.x*c2.x + t2.y*c2.y + t2.z*c2.z + t2.w*c2.w;
            // complete the 48-length dot across the 4-lane group
            dot += __shfl_xor(dot, 1, 4);
            dot += __shfl_xor(dot, 2, 4);
            acc += dot * dot;       // uniform across the 4 lanes
        }
    }

    if (sub == 0) {
        atomicAdd(&P[(size_t)i * NM + m], acc * SCALE_C);
    }
}

// ---------------------------------------------------------------------------
// Kernel 4: A[m] = sum_k (omega[k]==omega[m]) * P[k,m]; out[i,m] = A[m].
// ---------------------------------------------------------------------------
__global__ __launch_bounds__(256) void k_final(
    const float* __restrict__ omega, const float* __restrict__ P,
    float* __restrict__ out)
{
    __shared__ float A[NM];
    int tid = threadIdx.x;
    if (tid < NM) {
        float om  = omega[tid];
        float acc = 0.0f;
        for (int k = 0; k < NM; ++k) {
            if (omega[k] == om) acc += P[(size_t)k * NM + tid];
        }
        A[tid] = acc;
    }
    __syncthreads();
    int base = blockIdx.x * 512;
    for (int idx = tid; idx < 512; idx += 256) {
        int o = base + idx;
        out[o] = A[o & (NM - 1)];
    }
}

// ---------------------------------------------------------------------------
extern "C" void kernel_launch(void* const* d_in, const int* in_sizes, int n_in,
                              void* d_out, int out_size, void* d_ws, size_t ws_size,
                              hipStream_t stream)
{
    const float* q     = (const float*)d_in[0];   // [128,3]
    const float* omega = (const float*)d_in[1];   // [128]
    const float* et    = (const float*)d_in[2];   // [3,16,128,128,48]
    const float* e     = (const float*)d_in[3];   // [3,16,48,64,128]
    const float* gv    = (const float*)d_in[4];   // [64,3]
    const float* G     = (const float*)d_in[5];   // [3]
    const float* Q     = (const float*)d_in[6];   // [128,3]
    float* out = (float*)d_out;                   // [128,128]

    unsigned char* glist  = (unsigned char*)d_ws + WS_GLIST;
    int*           gcount = (int*)((char*)d_ws + WS_GCOUNT);
    float*         P      = (float*)((char*)d_ws + WS_P);
    float*         ec     = (float*)((char*)d_ws + WS_EC);

    k_prep  <<<64,   256, 0, stream>>>(q, gv, G, Q, glist, gcount, P);
    k_gather<<<1152, 256, 0, stream>>>(e, glist, gcount, ec);
    k_main  <<<1024, 256, 0, stream>>>(et, ec, gcount, P);
    k_final <<<32,   256, 0, stream>>>(omega, P, out);
}